// Round 16
// baseline (95.082 us; speedup 1.0000x reference)
//
#include <hip/hip_runtime.h>

#define T_ 4
#define E_ 1024
#define H_ 16
#define D_ 128
#define C_ 2048
#define QK_SCALE 0.08838834764831845f
#define LOG2E 1.4426950408889634f

typedef short s16x8 __attribute__((ext_vector_type(8)));
typedef float f32x4 __attribute__((ext_vector_type(4)));

__device__ __forceinline__ unsigned short f2bf(float x) {
    unsigned u = __builtin_bit_cast(unsigned, x);
    u = (u + 0x7FFFu + ((u >> 16) & 1u)) >> 16;
    return (unsigned short)u;
}

__device__ __forceinline__ unsigned cvt_pk(float lo, float hi) {
    unsigned r;
    asm("v_cvt_pk_bf16_f32 %0, %1, %2" : "=v"(r) : "v"(lo), "v"(hi));
    return r;
}

#define MFMA16(a, b, c) __builtin_amdgcn_mfma_f32_16x16x32_bf16((a), (b), (c), 0, 0, 0)

__device__ __forceinline__ void gload_lds16(const unsigned short* g, unsigned short* l) {
    __builtin_amdgcn_global_load_lds(
        (const __attribute__((address_space(1))) unsigned int*)g,
        (__attribute__((address_space(3))) unsigned int*)l, 16, 0, 0);
}

// ---------------- fused 7-tensor f32 -> bf16 convert ----------------
__global__ __launch_bounds__(256) void cvt7_kernel(
    const float* __restrict__ q, const float* __restrict__ k, const float* __restrict__ v,
    const float* __restrict__ wq, const float* __restrict__ wk, const float* __restrict__ wv,
    const float* __restrict__ wo,
    unsigned short* __restrict__ base, unsigned short* __restrict__ wo16)
{
    const int b = blockIdx.x;
    const float* src;
    unsigned short* dst;
    int lb;
    if (b < 256)       { src = q;  dst = base;            lb = b; }
    else if (b < 512)  { src = k;  dst = base + 524288;   lb = b - 256; }
    else if (b < 768)  { src = v;  dst = base + 1048576;  lb = b - 512; }
    else if (b < 896)  { src = wq; dst = base + 1572864;  lb = b - 768; }
    else if (b < 1024) { src = wk; dst = base + 1835008;  lb = b - 896; }
    else if (b < 1152) { src = wv; dst = base + 2097152;  lb = b - 1024; }
    else               { src = wo; dst = wo16;            lb = b - 1152; }
    const int i = (lb * 256 + threadIdx.x) * 8;
    float4 a = *reinterpret_cast<const float4*>(src + i);
    float4 c = *reinterpret_cast<const float4*>(src + i + 4);
    s16x8 r;
    r[0] = (short)f2bf(a.x); r[1] = (short)f2bf(a.y);
    r[2] = (short)f2bf(a.z); r[3] = (short)f2bf(a.w);
    r[4] = (short)f2bf(c.x); r[5] = (short)f2bf(c.y);
    r[6] = (short)f2bf(c.z); r[7] = (short)f2bf(c.w);
    *reinterpret_cast<s16x8*>(dst + i) = r;
}

// ---------------- K1: QKV projection (bf16 in, bf16 out, LDS-staged) ----------------
__global__ __launch_bounds__(256) void qkv_kernel(
    const unsigned short* __restrict__ Xq, const unsigned short* __restrict__ Xk,
    const unsigned short* __restrict__ Xv,
    const unsigned short* __restrict__ Wq_, const unsigned short* __restrict__ Wk_,
    const unsigned short* __restrict__ Wv_,
    const float* __restrict__ bq_, const float* __restrict__ bk_, const float* __restrict__ bv_,
    unsigned short* __restrict__ oq, unsigned short* __restrict__ okk,
    unsigned short* __restrict__ ov)
{
    __shared__ unsigned short S[2][128 * 128];  // [0]=X tile, [1]=W tile; reused as Tile

    const int z = blockIdx.z;
    const unsigned short* X = (z == 0) ? Xq : (z == 1) ? Xk : Xv;
    const unsigned short* W = (z == 0) ? Wq_ : (z == 1) ? Wk_ : Wv_;
    const float* Bv = (z == 0) ? bq_ : (z == 1) ? bk_ : bv_;
    unsigned short* out = (z == 0) ? oq : (z == 1) ? okk : ov;
    const float scale = (z == 0) ? (QK_SCALE * LOG2E) : 1.0f;

    const int tid = threadIdx.x;
    const int w = tid >> 6;
    const int lane = tid & 63;
    const int lr = lane & 15;
    const int lg = lane >> 4;
    const int nbase = blockIdx.y * 128;
    const size_t xrow0 = (size_t)blockIdx.x * 128;

#pragma unroll
    for (int it = 0; it < 8; ++it) {
        const int f = it * 256 + tid;
        const int kk = f >> 4;
        const int cs = ((f & 15) * 8) ^ ((kk & 7) << 3);
        gload_lds16(&X[(xrow0 + kk) * D_ + cs], &S[0][f * 8]);
        gload_lds16(&W[(size_t)(nbase + kk) * D_ + cs], &S[1][f * 8]);
    }
    __syncthreads();

    const int key = (lr & 7) << 3;
    s16x8 af[2][4];
#pragma unroll
    for (int mi = 0; mi < 2; ++mi)
#pragma unroll
        for (int kc = 0; kc < 4; ++kc)
            af[mi][kc] = *reinterpret_cast<const s16x8*>(
                &S[0][(w * 32 + mi * 16 + lr) * 128 + ((kc * 32 + lg * 8) ^ key)]);

    f32x4 acc[2][8];
#pragma unroll
    for (int mi = 0; mi < 2; ++mi)
#pragma unroll
        for (int n = 0; n < 8; ++n) acc[mi][n] = f32x4{0.f, 0.f, 0.f, 0.f};

#pragma unroll
    for (int n = 0; n < 8; ++n) {
        s16x8 bf[4];
#pragma unroll
        for (int kc = 0; kc < 4; ++kc)
            bf[kc] = *reinterpret_cast<const s16x8*>(
                &S[1][(n * 16 + lr) * 128 + ((kc * 32 + lg * 8) ^ key)]);
#pragma unroll
        for (int mi = 0; mi < 2; ++mi)
#pragma unroll
            for (int kc = 0; kc < 4; ++kc)
                acc[mi][n] = MFMA16(af[mi][kc], bf[kc], acc[mi][n]);
    }

    float bias[8];
#pragma unroll
    for (int n = 0; n < 8; ++n) bias[n] = Bv[nbase + n * 16 + lr];

    __syncthreads();
    unsigned short* Tile = &S[0][0];  // pitch 136

    if (z < 2) {
#pragma unroll
        for (int mi = 0; mi < 2; ++mi)
#pragma unroll
            for (int i = 0; i < 4; ++i) {
                const int rowl = w * 32 + mi * 16 + lg * 4 + i;
                float v0 = (acc[mi][0][i] + bias[0]) * scale;
                float v1 = (acc[mi][1][i] + bias[1]) * scale;
                float v2 = (acc[mi][2][i] + bias[2]) * scale;
                float v3 = (acc[mi][3][i] + bias[3]) * scale;
                float v4 = (acc[mi][4][i] + bias[4]) * scale;
                float v5 = (acc[mi][5][i] + bias[5]) * scale;
                float v6 = (acc[mi][6][i] + bias[6]) * scale;
                float v7 = (acc[mi][7][i] + bias[7]) * scale;
                union { s16x8 s; unsigned u[4]; } pk;
                pk.u[0] = cvt_pk(v0, v1);
                pk.u[1] = cvt_pk(v2, v3);
                pk.u[2] = cvt_pk(v4, v5);
                pk.u[3] = cvt_pk(v6, v7);
                *reinterpret_cast<s16x8*>(&Tile[rowl * 136 + 8 * lr]) = pk.s;
            }
    } else {
#pragma unroll
        for (int n = 0; n < 8; ++n) {
            union { s16x8 s; unsigned u[4]; } pk;
            pk.u[0] = cvt_pk(acc[0][n][0] + bias[n], acc[0][n][1] + bias[n]);
            pk.u[1] = cvt_pk(acc[0][n][2] + bias[n], acc[0][n][3] + bias[n]);
            pk.u[2] = cvt_pk(acc[1][n][0] + bias[n], acc[1][n][1] + bias[n]);
            pk.u[3] = cvt_pk(acc[1][n][2] + bias[n], acc[1][n][3] + bias[n]);
            *reinterpret_cast<s16x8*>(&Tile[(n * 16 + lr) * 136 + w * 32 + 8 * lg]) = pk.s;
        }
    }
    __syncthreads();

    const int t = (blockIdx.x * 128) >> 10;
    const int e0 = (blockIdx.x * 128) & 1023;
    const int hh = blockIdx.y;
    const int row16 = tid >> 4;
    const int c8 = (tid & 15) * 8;
    if (z < 2) {
        unsigned short* dst = out + (((size_t)(t * H_ + hh) * E_ + e0) * D_);
#pragma unroll
        for (int j = 0; j < 8; ++j) {
            const int row = j * 16 + row16;
            *reinterpret_cast<s16x8*>(dst + (size_t)row * D_ + c8) =
                *reinterpret_cast<const s16x8*>(&Tile[row * 136 + c8]);
        }
    } else {
        unsigned short* dst = out + ((size_t)(t * H_ + hh) * D_) * E_ + e0;
#pragma unroll
        for (int j = 0; j < 8; ++j) {
            const int row = j * 16 + row16;
            *reinterpret_cast<s16x8*>(dst + (size_t)row * E_ + c8) =
                *reinterpret_cast<const s16x8*>(&Tile[row * 136 + c8]);
        }
    }
}

// ---------------- K2: causal flash attention (dual-qblk waves) ----------------
// grid (T*H, 4), 512 thr = 8 waves. Block p handles qblk A=7-p AND B=p; each
// wave owns slice w of both. K/V fragments read from LDS ONCE per pass and
// feed both q-tiles (doB => doA since B < A): halves LDS b128 traffic/q-row
// and halves KV staging. 256 blocks = 1/CU.
__global__ __launch_bounds__(512, 2) void attn_kernel(
    const unsigned short* __restrict__ Q, const unsigned short* __restrict__ K,
    const unsigned short* __restrict__ Vt, unsigned short* __restrict__ O)
{
    __shared__ unsigned short K_lds[2][64 * 128];   // [kk][c] = K[kv0+kk][c ^ ((kk&7)<<3)]
    __shared__ unsigned short Vt_lds[2][128 * 64];  // [d][p]  = Vperm[d][kv0 + (p ^ ((d&7)<<3))]

    const int tid = threadIdx.x;
    const int w = tid >> 6;
    const int lane = tid & 63;
    const int lr = lane & 15;
    const int g = lane >> 4;
    const int th = blockIdx.x;
    const int t = th >> 4;
    const int h = th & 15;
    const int p = blockIdx.y;               // 0..3
    const int qA = 7 - p;
    const int qB = p;
    const int q0A = qA * 128 + w * 16;
    const int q0B = qB * 128 + w * 16;
    const int nkv = 2 * qA + 2;

    const unsigned short* Qh = Q + th * (E_ * D_);
    const unsigned short* Kh = K + th * (E_ * D_);
    const unsigned short* Vth = Vt + th * (D_ * E_);

    // hoisted staging sources (2 K-chunks + 2 V-chunks per thread)
    const int fA = tid, fB = 512 + tid;
    const unsigned short* gkA = Kh + (fA >> 4) * D_ + (((fA & 15) * 8) ^ (((fA >> 4) & 7) << 3));
    const unsigned short* gkB = Kh + (fB >> 4) * D_ + (((fB & 15) * 8) ^ (((fB >> 4) & 7) << 3));
    const unsigned short* gvA = Vth + (fA >> 3) * E_ + (((fA & 7) * 8) ^ (((fA >> 3) & 7) << 3));
    const unsigned short* gvB = Vth + (fB >> 3) * E_ + (((fB & 7) * 8) ^ (((fB >> 3) & 7) << 3));

    // Q as B-fragments for both q-tiles (pre-scaled in qkv)
    s16x8 qbA[4], qbB[4];
#pragma unroll
    for (int kc = 0; kc < 4; ++kc) {
        qbA[kc] = *reinterpret_cast<const s16x8*>(&Qh[(q0A + lr) * D_ + kc * 32 + g * 8]);
        qbB[kc] = *reinterpret_cast<const s16x8*>(&Qh[(q0B + lr) * D_ + kc * 32 + g * 8]);
    }

    s16x8 ones;
#pragma unroll
    for (int j = 0; j < 8; ++j) ones[j] = (short)0x3F80;

    f32x4 otA[8], otB[8];
    f32x4 lacA, lacB;
    float mA = -1e30f, mB = -1e30f;
#pragma unroll
    for (int dt = 0; dt < 8; ++dt) {
        otA[dt] = f32x4{0.f, 0.f, 0.f, 0.f};
        otB[dt] = f32x4{0.f, 0.f, 0.f, 0.f};
    }
    lacA = f32x4{0.f, 0.f, 0.f, 0.f};
    lacB = f32x4{0.f, 0.f, 0.f, 0.f};

    // prologue: stage tile 0
    gload_lds16(gkA, &K_lds[0][fA * 8]);
    gload_lds16(gkB, &K_lds[0][fB * 8]);
    gload_lds16(gvA, &Vt_lds[0][fA * 8]);
    gload_lds16(gvB, &Vt_lds[0][fB * 8]);
    gkA += 64 * D_; gkB += 64 * D_; gvA += 64; gvB += 64;

    int cur = 0;
    for (int kb = 0; kb < nkv; ++kb) {
        const int kv0 = kb * 64;
        __syncthreads();

        if (kb + 1 < nkv) {
            gload_lds16(gkA, &K_lds[cur ^ 1][fA * 8]);
            gload_lds16(gkB, &K_lds[cur ^ 1][fB * 8]);
            gload_lds16(gvA, &Vt_lds[cur ^ 1][fA * 8]);
            gload_lds16(gvB, &Vt_lds[cur ^ 1][fB * 8]);
            gkA += 64 * D_; gkB += 64 * D_; gvA += 64; gvB += 64;
        }

        if (kv0 <= q0A + 15) {          // doA (doB implies doA)
            const bool doB = (kv0 <= q0B + 15);
            const unsigned short* Kb = K_lds[cur];
            const unsigned short* Vb = Vt_lds[cur];
            const int key = (lr & 7) << 3;

            // S^T: K-frags read ONCE, feed both q-tiles
            f32x4 stA[4], stB[4];
            __builtin_amdgcn_s_setprio(1);
#pragma unroll
            for (int kvi = 0; kvi < 4; ++kvi) {
                s16x8 kf[4];
#pragma unroll
                for (int kc = 0; kc < 4; ++kc)
                    kf[kc] = *reinterpret_cast<const s16x8*>(
                        &Kb[(kvi * 16 + lr) * 128 + ((kc * 32 + g * 8) ^ key)]);
                f32x4 a = f32x4{0.f, 0.f, 0.f, 0.f};
#pragma unroll
                for (int kc = 0; kc < 4; ++kc) a = MFMA16(kf[kc], qbA[kc], a);
                stA[kvi] = a;
                if (doB) {
                    f32x4 b = f32x4{0.f, 0.f, 0.f, 0.f};
#pragma unroll
                    for (int kc = 0; kc < 4; ++kc) b = MFMA16(kf[kc], qbB[kc], b);
                    stB[kvi] = b;
                }
            }
            __builtin_amdgcn_s_setprio(0);

            // causal mask (diagonal tiles only)
            if (kv0 + 63 > q0A) {
                const int q = q0A + lr;
#pragma unroll
                for (int kvi = 0; kvi < 4; ++kvi)
#pragma unroll
                    for (int i = 0; i < 4; ++i) {
                        const int kv = kv0 + kvi * 16 + g * 4 + i;
                        if (kv > q) stA[kvi][i] = -1e30f;
                    }
            }
            if (doB && (kv0 + 63 > q0B)) {
                const int q = q0B + lr;
#pragma unroll
                for (int kvi = 0; kvi < 4; ++kvi)
#pragma unroll
                    for (int i = 0; i < 4; ++i) {
                        const int kv = kv0 + kvi * 16 + g * 4 + i;
                        if (kv > q) stB[kvi][i] = -1e30f;
                    }
            }

            // softmax A
            {
                float a0 = fmaxf(fmaxf(stA[0][0], stA[0][1]), fmaxf(stA[0][2], stA[0][3]));
                float a1 = fmaxf(fmaxf(stA[1][0], stA[1][1]), fmaxf(stA[1][2], stA[1][3]));
                float a2 = fmaxf(fmaxf(stA[2][0], stA[2][1]), fmaxf(stA[2][2], stA[2][3]));
                float a3 = fmaxf(fmaxf(stA[3][0], stA[3][1]), fmaxf(stA[3][2], stA[3][3]));
                float pm = fmaxf(fmaxf(a0, a1), fmaxf(a2, a3));
                pm = fmaxf(pm, __shfl_xor(pm, 16));
                pm = fmaxf(pm, __shfl_xor(pm, 32));
                if (__any(pm > mA + 8.f)) {
                    const float mn = fmaxf(mA, pm);
                    const float esc = exp2f(mA - mn);
                    mA = mn;
                    lacA *= esc;
#pragma unroll
                    for (int dt = 0; dt < 8; ++dt) otA[dt] *= esc;
                }
            }
            s16x8 pbA[2];
#pragma unroll
            for (int kc = 0; kc < 2; ++kc) {
                float e0 = exp2f(stA[2 * kc][0] - mA);
                float e1 = exp2f(stA[2 * kc][1] - mA);
                float e2 = exp2f(stA[2 * kc][2] - mA);
                float e3 = exp2f(stA[2 * kc][3] - mA);
                float f0 = exp2f(stA[2 * kc + 1][0] - mA);
                float f1 = exp2f(stA[2 * kc + 1][1] - mA);
                float f2 = exp2f(stA[2 * kc + 1][2] - mA);
                float f3 = exp2f(stA[2 * kc + 1][3] - mA);
                union { s16x8 s; unsigned u[4]; } pk;
                pk.u[0] = cvt_pk(e0, e1);
                pk.u[1] = cvt_pk(e2, e3);
                pk.u[2] = cvt_pk(f0, f1);
                pk.u[3] = cvt_pk(f2, f3);
                pbA[kc] = pk.s;
            }
            lacA = MFMA16(ones, pbA[0], lacA);
            lacA = MFMA16(ones, pbA[1], lacA);

            // softmax B (subset)
            s16x8 pbB[2];
            if (doB) {
                float a0 = fmaxf(fmaxf(stB[0][0], stB[0][1]), fmaxf(stB[0][2], stB[0][3]));
                float a1 = fmaxf(fmaxf(stB[1][0], stB[1][1]), fmaxf(stB[1][2], stB[1][3]));
                float a2 = fmaxf(fmaxf(stB[2][0], stB[2][1]), fmaxf(stB[2][2], stB[2][3]));
                float a3 = fmaxf(fmaxf(stB[3][0], stB[3][1]), fmaxf(stB[3][2], stB[3][3]));
                float pm = fmaxf(fmaxf(a0, a1), fmaxf(a2, a3));
                pm = fmaxf(pm, __shfl_xor(pm, 16));
                pm = fmaxf(pm, __shfl_xor(pm, 32));
                if (__any(pm > mB + 8.f)) {
                    const float mn = fmaxf(mB, pm);
                    const float esc = exp2f(mB - mn);
                    mB = mn;
                    lacB *= esc;
#pragma unroll
                    for (int dt = 0; dt < 8; ++dt) otB[dt] *= esc;
                }
#pragma unroll
                for (int kc = 0; kc < 2; ++kc) {
                    float e0 = exp2f(stB[2 * kc][0] - mB);
                    float e1 = exp2f(stB[2 * kc][1] - mB);
                    float e2 = exp2f(stB[2 * kc][2] - mB);
                    float e3 = exp2f(stB[2 * kc][3] - mB);
                    float f0 = exp2f(stB[2 * kc + 1][0] - mB);
                    float f1 = exp2f(stB[2 * kc + 1][1] - mB);
                    float f2 = exp2f(stB[2 * kc + 1][2] - mB);
                    float f3 = exp2f(stB[2 * kc + 1][3] - mB);
                    union { s16x8 s; unsigned u[4]; } pk;
                    pk.u[0] = cvt_pk(e0, e1);
                    pk.u[1] = cvt_pk(e2, e3);
                    pk.u[2] = cvt_pk(f0, f1);
                    pk.u[3] = cvt_pk(f2, f3);
                    pbB[kc] = pk.s;
                }
                lacB = MFMA16(ones, pbB[0], lacB);
                lacB = MFMA16(ones, pbB[1], lacB);
            }

            // PV: V-frags read ONCE, feed both q-tiles
            __builtin_amdgcn_s_setprio(1);
            if (doB) {
#pragma unroll
                for (int dt = 0; dt < 8; ++dt) {
                    const int rb = (dt * 16 + lr) * 64;
#pragma unroll
                    for (int kc = 0; kc < 2; ++kc) {
                        s16x8 va = *reinterpret_cast<const s16x8*>(
                            &Vb[rb + ((kc * 32 + 8 * g) ^ key)]);
                        otA[dt] = MFMA16(va, pbA[kc], otA[dt]);
                        otB[dt] = MFMA16(va, pbB[kc], otB[dt]);
                    }
                }
            } else {
#pragma unroll
                for (int dt = 0; dt < 8; ++dt) {
                    const int rb = (dt * 16 + lr) * 64;
#pragma unroll
                    for (int kc = 0; kc < 2; ++kc) {
                        s16x8 va = *reinterpret_cast<const s16x8*>(
                            &Vb[rb + ((kc * 32 + 8 * g) ^ key)]);
                        otA[dt] = MFMA16(va, pbA[kc], otA[dt]);
                    }
                }
            }
            __builtin_amdgcn_s_setprio(0);
        }
        cur ^= 1;
    }

    // epilogue: both q-tiles
    unsigned short* Ob = O + (size_t)t * E_ * C_ + h * D_;
    {
        const float rl = 1.0f / lacA[0];
        const int q = q0A + lr;
#pragma unroll
        for (int dt = 0; dt < 8; ++dt) {
            uint2 val;
            val.x = cvt_pk(otA[dt][0] * rl, otA[dt][1] * rl);
            val.y = cvt_pk(otA[dt][2] * rl, otA[dt][3] * rl);
            *reinterpret_cast<uint2*>(&Ob[(size_t)q * C_ + dt * 16 + 4 * g]) = val;
        }
    }
    {
        const float rl = 1.0f / lacB[0];
        const int q = q0B + lr;
#pragma unroll
        for (int dt = 0; dt < 8; ++dt) {
            uint2 val;
            val.x = cvt_pk(otB[dt][0] * rl, otB[dt][1] * rl);
            val.y = cvt_pk(otB[dt][2] * rl, otB[dt][3] * rl);
            *reinterpret_cast<uint2*>(&Ob[(size_t)q * C_ + dt * 16 + 4 * g]) = val;
        }
    }
}

// ---------------- K3a: output projection partials (M=4096, N=128, K=2048/4) ----------------
__global__ __launch_bounds__(256) void oproj_partial(
    const unsigned short* __restrict__ A, const unsigned short* __restrict__ Wo16,
    float* __restrict__ part)
{
    const int tid = threadIdx.x;
    const int w = tid >> 6;
    const int lane = tid & 63;
    const int lr = lane & 15;
    const int lg = lane >> 4;
    const int mbase = blockIdx.x * 16;
    const int ncol = w * 32;
    const int k0 = blockIdx.y * 512;
    float* myp = part + (size_t)blockIdx.y * (4096 * 128);

    f32x4 acc0 = f32x4{0.f, 0.f, 0.f, 0.f};
    f32x4 acc1 = f32x4{0.f, 0.f, 0.f, 0.f};
    const unsigned short* Arow = A + (size_t)(mbase + lr) * C_ + k0;
    const unsigned short* W0 = Wo16 + (size_t)(ncol + lr) * C_ + k0;
    const unsigned short* W1 = Wo16 + (size_t)(ncol + 16 + lr) * C_ + k0;

#pragma unroll 8
    for (int kb = 0; kb < 16; ++kb) {
        const int ko = kb * 32 + lg * 8;
        s16x8 af = *reinterpret_cast<const s16x8*>(Arow + ko);
        s16x8 b0 = *reinterpret_cast<const s16x8*>(W0 + ko);
        s16x8 b1 = *reinterpret_cast<const s16x8*>(W1 + ko);
        acc0 = MFMA16(af, b0, acc0);
        acc1 = MFMA16(af, b1, acc1);
    }

#pragma unroll
    for (int n = 0; n < 2; ++n) {
        const f32x4 acc = n ? acc1 : acc0;
        const int col = ncol + n * 16 + lr;
#pragma unroll
        for (int i = 0; i < 4; ++i)
            myp[(mbase + lg * 4 + i) * D_ + col] = acc[i];
    }
}

// ---------------- K3b: reduce 4 partials + bias -> out ----------------
__global__ __launch_bounds__(256) void oproj_reduce(
    const float* __restrict__ part, const float* __restrict__ bo,
    float* __restrict__ out)
{
    const int iv = blockIdx.x * 256 + threadIdx.x;
    const size_t seg = (size_t)4096 * 128;
    float4 s = *reinterpret_cast<const float4*>(part + (size_t)iv * 4);
#pragma unroll
    for (int y = 1; y < 4; ++y) {
        float4 v = *reinterpret_cast<const float4*>(part + y * seg + (size_t)iv * 4);
        s.x += v.x; s.y += v.y; s.z += v.z; s.w += v.w;
    }
    const float4 b = *reinterpret_cast<const float4*>(bo + ((iv & 31) * 4));
    s.x += b.x; s.y += b.y; s.z += b.z; s.w += b.w;
    *reinterpret_cast<float4*>(out + (size_t)iv * 4) = s;
}

extern "C" void kernel_launch(void* const* d_in, const int* in_sizes, int n_in,
                              void* d_out, int out_size, void* d_ws, size_t ws_size,
                              hipStream_t stream) {
    const float* key   = (const float*)d_in[0];
    const float* value = (const float*)d_in[1];
    const float* query = (const float*)d_in[2];
    const float* Wq = (const float*)d_in[3];
    const float* bq = (const float*)d_in[4];
    const float* Wk = (const float*)d_in[5];
    const float* bk = (const float*)d_in[6];
    const float* Wv = (const float*)d_in[7];
    const float* bv = (const float*)d_in[8];
    const float* Wo = (const float*)d_in[9];
    const float* bo = (const float*)d_in[10];
    float* out = (float*)d_out;

    unsigned short* ws = (unsigned short*)d_ws;
    const size_t QKV_ELEMS = (size_t)T_ * H_ * E_ * D_;  // 8388608
    unsigned short* q_ws = ws;
    unsigned short* k_ws = ws + QKV_ELEMS;
    unsigned short* v_ws = ws + 2 * QKV_ELEMS;            // V^T [T][H][D][E], e-permuted
    unsigned short* att_ws = ws + 3 * QKV_ELEMS;
    unsigned short* wo16_ws = ws + 4 * QKV_ELEMS;
    float* part_ws = (float*)k_ws;                        // k_ws dead after attn (8MB used)

    unsigned short* xq16 = att_ws;
    unsigned short* xk16 = att_ws + 524288;
    unsigned short* xv16 = att_ws + 1048576;
    unsigned short* wq16 = att_ws + 1572864;
    unsigned short* wk16 = att_ws + 1835008;
    unsigned short* wv16 = att_ws + 2097152;

    cvt7_kernel<<<dim3(1280), 256, 0, stream>>>(query, key, value, Wq, Wk, Wv, Wo,
                                                att_ws, wo16_ws);
    qkv_kernel<<<dim3(32, 16, 3), 256, 0, stream>>>(xq16, xk16, xv16,
                                                    wq16, wk16, wv16,
                                                    bq, bk, bv,
                                                    q_ws, k_ws, v_ws);
    attn_kernel<<<dim3(64, 4), 512, 0, stream>>>(q_ws, k_ws, v_ws, att_ws);
    oproj_partial<<<dim3(256, 4), 256, 0, stream>>>(att_ws, wo16_ws, part_ws);
    oproj_reduce<<<dim3(512), 256, 0, stream>>>(part_ws, bo, out);
}

// Round 17
// 89.664 us; speedup vs baseline: 1.0604x; 1.0604x over previous
//
#include <hip/hip_runtime.h>

#define T_ 4
#define E_ 1024
#define H_ 16
#define D_ 128
#define C_ 2048
#define QK_SCALE 0.08838834764831845f
#define LOG2E 1.4426950408889634f

typedef short s16x8 __attribute__((ext_vector_type(8)));
typedef float f32x4 __attribute__((ext_vector_type(4)));

__device__ __forceinline__ unsigned short f2bf(float x) {
    unsigned u = __builtin_bit_cast(unsigned, x);
    u = (u + 0x7FFFu + ((u >> 16) & 1u)) >> 16;
    return (unsigned short)u;
}

__device__ __forceinline__ unsigned cvt_pk(float lo, float hi) {
    unsigned r;
    asm("v_cvt_pk_bf16_f32 %0, %1, %2" : "=v"(r) : "v"(lo), "v"(hi));
    return r;
}

#define MFMA16(a, b, c) __builtin_amdgcn_mfma_f32_16x16x32_bf16((a), (b), (c), 0, 0, 0)

__device__ __forceinline__ void gload_lds16(const unsigned short* g, unsigned short* l) {
    __builtin_amdgcn_global_load_lds(
        (const __attribute__((address_space(1))) unsigned int*)g,
        (__attribute__((address_space(3))) unsigned int*)l, 16, 0, 0);
}

// ---------------- fused 7-tensor f32 -> bf16 convert ----------------
__global__ __launch_bounds__(256) void cvt7_kernel(
    const float* __restrict__ q, const float* __restrict__ k, const float* __restrict__ v,
    const float* __restrict__ wq, const float* __restrict__ wk, const float* __restrict__ wv,
    const float* __restrict__ wo,
    unsigned short* __restrict__ base, unsigned short* __restrict__ wo16)
{
    const int b = blockIdx.x;
    const float* src;
    unsigned short* dst;
    int lb;
    if (b < 256)       { src = q;  dst = base;            lb = b; }
    else if (b < 512)  { src = k;  dst = base + 524288;   lb = b - 256; }
    else if (b < 768)  { src = v;  dst = base + 1048576;  lb = b - 512; }
    else if (b < 896)  { src = wq; dst = base + 1572864;  lb = b - 768; }
    else if (b < 1024) { src = wk; dst = base + 1835008;  lb = b - 896; }
    else if (b < 1152) { src = wv; dst = base + 2097152;  lb = b - 1024; }
    else               { src = wo; dst = wo16;            lb = b - 1152; }
    const int i = (lb * 256 + threadIdx.x) * 8;
    float4 a = *reinterpret_cast<const float4*>(src + i);
    float4 c = *reinterpret_cast<const float4*>(src + i + 4);
    s16x8 r;
    r[0] = (short)f2bf(a.x); r[1] = (short)f2bf(a.y);
    r[2] = (short)f2bf(a.z); r[3] = (short)f2bf(a.w);
    r[4] = (short)f2bf(c.x); r[5] = (short)f2bf(c.y);
    r[6] = (short)f2bf(c.z); r[7] = (short)f2bf(c.w);
    *reinterpret_cast<s16x8*>(dst + i) = r;
}

// ---------------- K1: QKV projection (bf16 in, bf16 out, LDS-staged) ----------------
__global__ __launch_bounds__(256) void qkv_kernel(
    const unsigned short* __restrict__ Xq, const unsigned short* __restrict__ Xk,
    const unsigned short* __restrict__ Xv,
    const unsigned short* __restrict__ Wq_, const unsigned short* __restrict__ Wk_,
    const unsigned short* __restrict__ Wv_,
    const float* __restrict__ bq_, const float* __restrict__ bk_, const float* __restrict__ bv_,
    unsigned short* __restrict__ oq, unsigned short* __restrict__ okk,
    unsigned short* __restrict__ ov)
{
    __shared__ unsigned short S[2][128 * 128];  // [0]=X tile, [1]=W tile; reused as Tile

    const int z = blockIdx.z;
    const unsigned short* X = (z == 0) ? Xq : (z == 1) ? Xk : Xv;
    const unsigned short* W = (z == 0) ? Wq_ : (z == 1) ? Wk_ : Wv_;
    const float* Bv = (z == 0) ? bq_ : (z == 1) ? bk_ : bv_;
    unsigned short* out = (z == 0) ? oq : (z == 1) ? okk : ov;
    const float scale = (z == 0) ? (QK_SCALE * LOG2E) : 1.0f;

    const int tid = threadIdx.x;
    const int w = tid >> 6;
    const int lane = tid & 63;
    const int lr = lane & 15;
    const int lg = lane >> 4;
    const int nbase = blockIdx.y * 128;
    const size_t xrow0 = (size_t)blockIdx.x * 128;

#pragma unroll
    for (int it = 0; it < 8; ++it) {
        const int f = it * 256 + tid;
        const int kk = f >> 4;
        const int cs = ((f & 15) * 8) ^ ((kk & 7) << 3);
        gload_lds16(&X[(xrow0 + kk) * D_ + cs], &S[0][f * 8]);
        gload_lds16(&W[(size_t)(nbase + kk) * D_ + cs], &S[1][f * 8]);
    }
    __syncthreads();

    const int key = (lr & 7) << 3;
    s16x8 af[2][4];
#pragma unroll
    for (int mi = 0; mi < 2; ++mi)
#pragma unroll
        for (int kc = 0; kc < 4; ++kc)
            af[mi][kc] = *reinterpret_cast<const s16x8*>(
                &S[0][(w * 32 + mi * 16 + lr) * 128 + ((kc * 32 + lg * 8) ^ key)]);

    f32x4 acc[2][8];
#pragma unroll
    for (int mi = 0; mi < 2; ++mi)
#pragma unroll
        for (int n = 0; n < 8; ++n) acc[mi][n] = f32x4{0.f, 0.f, 0.f, 0.f};

#pragma unroll
    for (int n = 0; n < 8; ++n) {
        s16x8 bf[4];
#pragma unroll
        for (int kc = 0; kc < 4; ++kc)
            bf[kc] = *reinterpret_cast<const s16x8*>(
                &S[1][(n * 16 + lr) * 128 + ((kc * 32 + lg * 8) ^ key)]);
#pragma unroll
        for (int mi = 0; mi < 2; ++mi)
#pragma unroll
            for (int kc = 0; kc < 4; ++kc)
                acc[mi][n] = MFMA16(af[mi][kc], bf[kc], acc[mi][n]);
    }

    float bias[8];
#pragma unroll
    for (int n = 0; n < 8; ++n) bias[n] = Bv[nbase + n * 16 + lr];

    __syncthreads();
    unsigned short* Tile = &S[0][0];  // pitch 136

    if (z < 2) {
#pragma unroll
        for (int mi = 0; mi < 2; ++mi)
#pragma unroll
            for (int i = 0; i < 4; ++i) {
                const int rowl = w * 32 + mi * 16 + lg * 4 + i;
                float v0 = (acc[mi][0][i] + bias[0]) * scale;
                float v1 = (acc[mi][1][i] + bias[1]) * scale;
                float v2 = (acc[mi][2][i] + bias[2]) * scale;
                float v3 = (acc[mi][3][i] + bias[3]) * scale;
                float v4 = (acc[mi][4][i] + bias[4]) * scale;
                float v5 = (acc[mi][5][i] + bias[5]) * scale;
                float v6 = (acc[mi][6][i] + bias[6]) * scale;
                float v7 = (acc[mi][7][i] + bias[7]) * scale;
                union { s16x8 s; unsigned u[4]; } pk;
                pk.u[0] = cvt_pk(v0, v1);
                pk.u[1] = cvt_pk(v2, v3);
                pk.u[2] = cvt_pk(v4, v5);
                pk.u[3] = cvt_pk(v6, v7);
                *reinterpret_cast<s16x8*>(&Tile[rowl * 136 + 8 * lr]) = pk.s;
            }
    } else {
#pragma unroll
        for (int n = 0; n < 8; ++n) {
            union { s16x8 s; unsigned u[4]; } pk;
            pk.u[0] = cvt_pk(acc[0][n][0] + bias[n], acc[0][n][1] + bias[n]);
            pk.u[1] = cvt_pk(acc[0][n][2] + bias[n], acc[0][n][3] + bias[n]);
            pk.u[2] = cvt_pk(acc[1][n][0] + bias[n], acc[1][n][1] + bias[n]);
            pk.u[3] = cvt_pk(acc[1][n][2] + bias[n], acc[1][n][3] + bias[n]);
            *reinterpret_cast<s16x8*>(&Tile[(n * 16 + lr) * 136 + w * 32 + 8 * lg]) = pk.s;
        }
    }
    __syncthreads();

    const int t = (blockIdx.x * 128) >> 10;
    const int e0 = (blockIdx.x * 128) & 1023;
    const int hh = blockIdx.y;
    const int row16 = tid >> 4;
    const int c8 = (tid & 15) * 8;
    if (z < 2) {
        unsigned short* dst = out + (((size_t)(t * H_ + hh) * E_ + e0) * D_);
#pragma unroll
        for (int j = 0; j < 8; ++j) {
            const int row = j * 16 + row16;
            *reinterpret_cast<s16x8*>(dst + (size_t)row * D_ + c8) =
                *reinterpret_cast<const s16x8*>(&Tile[row * 136 + c8]);
        }
    } else {
        unsigned short* dst = out + ((size_t)(t * H_ + hh) * D_) * E_ + e0;
#pragma unroll
        for (int j = 0; j < 8; ++j) {
            const int row = j * 16 + row16;
            *reinterpret_cast<s16x8*>(dst + (size_t)row * E_ + c8) =
                *reinterpret_cast<const s16x8*>(&Tile[row * 136 + c8]);
        }
    }
}

// ---------------- K2: causal flash attention (S^T, 8 waves x 16 q-rows) ----------------
// R15 build; A/B: s_setprio removed (lockstep waves -> no role diversity).
__global__ __launch_bounds__(512, 4) void attn_kernel(
    const unsigned short* __restrict__ Q, const unsigned short* __restrict__ K,
    const unsigned short* __restrict__ Vt, unsigned short* __restrict__ O)
{
    __shared__ unsigned short K_lds[2][64 * 128];   // [kk][c] = K[kv0+kk][c ^ ((kk&7)<<3)]
    __shared__ unsigned short Vt_lds[2][128 * 64];  // [d][p]  = Vperm[d][kv0 + (p ^ ((d&7)<<3))]

    const int tid = threadIdx.x;
    const int w = tid >> 6;
    const int lane = tid & 63;
    const int lr = lane & 15;
    const int g = lane >> 4;
    const int th = blockIdx.x;
    const int t = th >> 4;
    const int h = th & 15;
    const int p = blockIdx.y;
    const int qblk = (p < 4) ? (7 - p) : (p - 4);
    const int q0w = qblk * 128 + w * 16;
    const int nkv = 2 * qblk + 2;

    const unsigned short* Qh = Q + th * (E_ * D_);
    const unsigned short* Kh = K + th * (E_ * D_);
    const unsigned short* Vth = Vt + th * (D_ * E_);

    // hoisted staging sources (2 K-chunks + 2 V-chunks per thread)
    const int fA = tid, fB = 512 + tid;
    const unsigned short* gkA = Kh + (fA >> 4) * D_ + (((fA & 15) * 8) ^ (((fA >> 4) & 7) << 3));
    const unsigned short* gkB = Kh + (fB >> 4) * D_ + (((fB & 15) * 8) ^ (((fB >> 4) & 7) << 3));
    const unsigned short* gvA = Vth + (fA >> 3) * E_ + (((fA & 7) * 8) ^ (((fA >> 3) & 7) << 3));
    const unsigned short* gvB = Vth + (fB >> 3) * E_ + (((fB & 7) * 8) ^ (((fB >> 3) & 7) << 3));

    // Q as B-fragments (cols = q rows), pre-scaled in qkv
    s16x8 qb[4];
#pragma unroll
    for (int kc = 0; kc < 4; ++kc)
        qb[kc] = *reinterpret_cast<const s16x8*>(
            &Qh[(q0w + lr) * D_ + kc * 32 + g * 8]);

    s16x8 ones;
#pragma unroll
    for (int j = 0; j < 8; ++j) ones[j] = (short)0x3F80;

    f32x4 ot[8];
    f32x4 lac;
    float m = -1e30f;
#pragma unroll
    for (int dt = 0; dt < 8; ++dt) ot[dt] = f32x4{0.f, 0.f, 0.f, 0.f};
    lac = f32x4{0.f, 0.f, 0.f, 0.f};

    // prologue: stage tile 0
    gload_lds16(gkA, &K_lds[0][fA * 8]);
    gload_lds16(gkB, &K_lds[0][fB * 8]);
    gload_lds16(gvA, &Vt_lds[0][fA * 8]);
    gload_lds16(gvB, &Vt_lds[0][fB * 8]);
    gkA += 64 * D_; gkB += 64 * D_; gvA += 64; gvB += 64;

    int cur = 0;
    for (int kb = 0; kb < nkv; ++kb) {
        const int kv0 = kb * 64;
        __syncthreads();

        if (kb + 1 < nkv) {
            gload_lds16(gkA, &K_lds[cur ^ 1][fA * 8]);
            gload_lds16(gkB, &K_lds[cur ^ 1][fB * 8]);
            gload_lds16(gvA, &Vt_lds[cur ^ 1][fA * 8]);
            gload_lds16(gvB, &Vt_lds[cur ^ 1][fB * 8]);
            gkA += 64 * D_; gkB += 64 * D_; gvA += 64; gvB += 64;
        }

        if (kv0 <= q0w + 15) {
            const unsigned short* Kb = K_lds[cur];
            const unsigned short* Vb = Vt_lds[cur];
            const int key = (lr & 7) << 3;

            // S^T[kv][q]: 4 kv tiles x 1 q tile
            f32x4 st[4];
#pragma unroll
            for (int kvi = 0; kvi < 4; ++kvi) {
                s16x8 kf[4];
#pragma unroll
                for (int kc = 0; kc < 4; ++kc)
                    kf[kc] = *reinterpret_cast<const s16x8*>(
                        &Kb[(kvi * 16 + lr) * 128 + ((kc * 32 + g * 8) ^ key)]);
                f32x4 a = f32x4{0.f, 0.f, 0.f, 0.f};
#pragma unroll
                for (int kc = 0; kc < 4; ++kc) a = MFMA16(kf[kc], qb[kc], a);
                st[kvi] = a;
            }

            // causal mask: only diagonal tiles (wave-uniform branch)
            if (kv0 + 63 > q0w) {
                const int q = q0w + lr;
#pragma unroll
                for (int kvi = 0; kvi < 4; ++kvi)
#pragma unroll
                    for (int i = 0; i < 4; ++i) {
                        const int kv = kv0 + kvi * 16 + g * 4 + i;
                        if (kv > q) st[kvi][i] = -1e30f;
                    }
            }

            // per-q-column max: lane-local over 16 vals, then xor-16/32
            float a0 = fmaxf(fmaxf(st[0][0], st[0][1]), fmaxf(st[0][2], st[0][3]));
            float a1 = fmaxf(fmaxf(st[1][0], st[1][1]), fmaxf(st[1][2], st[1][3]));
            float a2 = fmaxf(fmaxf(st[2][0], st[2][1]), fmaxf(st[2][2], st[2][3]));
            float a3 = fmaxf(fmaxf(st[3][0], st[3][1]), fmaxf(st[3][2], st[3][3]));
            float pm = fmaxf(fmaxf(a0, a1), fmaxf(a2, a3));
            pm = fmaxf(pm, __shfl_xor(pm, 16));
            pm = fmaxf(pm, __shfl_xor(pm, 32));

            // defer-max: rescale only when max grew past threshold
            if (__any(pm > m + 8.f)) {
                const float mn = fmaxf(m, pm);
                const float esc = exp2f(m - mn);
                m = mn;
                lac *= esc;
#pragma unroll
                for (int dt = 0; dt < 8; ++dt) ot[dt] *= esc;
            }

            // P^T -> bf16 B-frags in registers
            s16x8 pb[2];
#pragma unroll
            for (int kc = 0; kc < 2; ++kc) {
                float e0 = exp2f(st[2 * kc][0] - m);
                float e1 = exp2f(st[2 * kc][1] - m);
                float e2 = exp2f(st[2 * kc][2] - m);
                float e3 = exp2f(st[2 * kc][3] - m);
                float f0 = exp2f(st[2 * kc + 1][0] - m);
                float f1 = exp2f(st[2 * kc + 1][1] - m);
                float f2 = exp2f(st[2 * kc + 1][2] - m);
                float f3 = exp2f(st[2 * kc + 1][3] - m);
                union { s16x8 s; unsigned u[4]; } pk;
                pk.u[0] = cvt_pk(e0, e1);
                pk.u[1] = cvt_pk(e2, e3);
                pk.u[2] = cvt_pk(f0, f1);
                pk.u[3] = cvt_pk(f2, f3);
                pb[kc] = pk.s;
            }

            // row-sum via ones-MFMA
            lac = MFMA16(ones, pb[0], lac);
            lac = MFMA16(ones, pb[1], lac);

            // O^T += V^T @ P^T  (A-frag: ONE b128 read, conflict-free)
#pragma unroll
            for (int dt = 0; dt < 8; ++dt) {
                const int rb = (dt * 16 + lr) * 64;
#pragma unroll
                for (int kc = 0; kc < 2; ++kc) {
                    s16x8 va = *reinterpret_cast<const s16x8*>(
                        &Vb[rb + ((kc * 32 + 8 * g) ^ key)]);
                    ot[dt] = MFMA16(va, pb[kc], ot[dt]);
                }
            }
        }
        cur ^= 1;
    }

    // epilogue: lane holds q=q0w+lr, d=dt*16+g*4+i -> b64 stores
    unsigned short* Ob = O + (size_t)t * E_ * C_ + h * D_;
    const float rl = 1.0f / lac[0];
    const int q = q0w + lr;
#pragma unroll
    for (int dt = 0; dt < 8; ++dt) {
        uint2 val;
        val.x = cvt_pk(ot[dt][0] * rl, ot[dt][1] * rl);
        val.y = cvt_pk(ot[dt][2] * rl, ot[dt][3] * rl);
        *reinterpret_cast<uint2*>(&Ob[(size_t)q * C_ + dt * 16 + 4 * g]) = val;
    }
}

// ---------------- K3a: output projection partials (M=4096, N=128, K=2048/4) ----------------
__global__ __launch_bounds__(256) void oproj_partial(
    const unsigned short* __restrict__ A, const unsigned short* __restrict__ Wo16,
    float* __restrict__ part)
{
    const int tid = threadIdx.x;
    const int w = tid >> 6;
    const int lane = tid & 63;
    const int lr = lane & 15;
    const int lg = lane >> 4;
    const int mbase = blockIdx.x * 16;
    const int ncol = w * 32;
    const int k0 = blockIdx.y * 512;
    float* myp = part + (size_t)blockIdx.y * (4096 * 128);

    f32x4 acc0 = f32x4{0.f, 0.f, 0.f, 0.f};
    f32x4 acc1 = f32x4{0.f, 0.f, 0.f, 0.f};
    const unsigned short* Arow = A + (size_t)(mbase + lr) * C_ + k0;
    const unsigned short* W0 = Wo16 + (size_t)(ncol + lr) * C_ + k0;
    const unsigned short* W1 = Wo16 + (size_t)(ncol + 16 + lr) * C_ + k0;

#pragma unroll 8
    for (int kb = 0; kb < 16; ++kb) {
        const int ko = kb * 32 + lg * 8;
        s16x8 af = *reinterpret_cast<const s16x8*>(Arow + ko);
        s16x8 b0 = *reinterpret_cast<const s16x8*>(W0 + ko);
        s16x8 b1 = *reinterpret_cast<const s16x8*>(W1 + ko);
        acc0 = MFMA16(af, b0, acc0);
        acc1 = MFMA16(af, b1, acc1);
    }

#pragma unroll
    for (int n = 0; n < 2; ++n) {
        const f32x4 acc = n ? acc1 : acc0;
        const int col = ncol + n * 16 + lr;
#pragma unroll
        for (int i = 0; i < 4; ++i)
            myp[(mbase + lg * 4 + i) * D_ + col] = acc[i];
    }
}

// ---------------- K3b: reduce 4 partials + bias -> out ----------------
__global__ __launch_bounds__(256) void oproj_reduce(
    const float* __restrict__ part, const float* __restrict__ bo,
    float* __restrict__ out)
{
    const int iv = blockIdx.x * 256 + threadIdx.x;
    const size_t seg = (size_t)4096 * 128;
    float4 s = *reinterpret_cast<const float4*>(part + (size_t)iv * 4);
#pragma unroll
    for (int y = 1; y < 4; ++y) {
        float4 v = *reinterpret_cast<const float4*>(part + y * seg + (size_t)iv * 4);
        s.x += v.x; s.y += v.y; s.z += v.z; s.w += v.w;
    }
    const float4 b = *reinterpret_cast<const float4*>(bo + ((iv & 31) * 4));
    s.x += b.x; s.y += b.y; s.z += b.z; s.w += b.w;
    *reinterpret_cast<float4*>(out + (size_t)iv * 4) = s;
}

extern "C" void kernel_launch(void* const* d_in, const int* in_sizes, int n_in,
                              void* d_out, int out_size, void* d_ws, size_t ws_size,
                              hipStream_t stream) {
    const float* key   = (const float*)d_in[0];
    const float* value = (const float*)d_in[1];
    const float* query = (const float*)d_in[2];
    const float* Wq = (const float*)d_in[3];
    const float* bq = (const float*)d_in[4];
    const float* Wk = (const float*)d_in[5];
    const float* bk = (const float*)d_in[6];
    const float* Wv = (const float*)d_in[7];
    const float* bv = (const float*)d_in[8];
    const float* Wo = (const float*)d_in[9];
    const float* bo = (const float*)d_in[10];
    float* out = (float*)d_out;

    unsigned short* ws = (unsigned short*)d_ws;
    const size_t QKV_ELEMS = (size_t)T_ * H_ * E_ * D_;  // 8388608
    unsigned short* q_ws = ws;
    unsigned short* k_ws = ws + QKV_ELEMS;
    unsigned short* v_ws = ws + 2 * QKV_ELEMS;            // V^T [T][H][D][E], e-permuted
    unsigned short* att_ws = ws + 3 * QKV_ELEMS;
    unsigned short* wo16_ws = ws + 4 * QKV_ELEMS;
    float* part_ws = (float*)k_ws;                        // k_ws dead after attn (8MB used)

    unsigned short* xq16 = att_ws;
    unsigned short* xk16 = att_ws + 524288;
    unsigned short* xv16 = att_ws + 1048576;
    unsigned short* wq16 = att_ws + 1572864;
    unsigned short* wk16 = att_ws + 1835008;
    unsigned short* wv16 = att_ws + 2097152;

    cvt7_kernel<<<dim3(1280), 256, 0, stream>>>(query, key, value, Wq, Wk, Wv, Wo,
                                                att_ws, wo16_ws);
    qkv_kernel<<<dim3(32, 16, 3), 256, 0, stream>>>(xq16, xk16, xv16,
                                                    wq16, wk16, wv16,
                                                    bq, bk, bv,
                                                    q_ws, k_ws, v_ws);
    attn_kernel<<<dim3(64, 8), 512, 0, stream>>>(q_ws, k_ws, v_ws, att_ws);
    oproj_partial<<<dim3(256, 4), 256, 0, stream>>>(att_ws, wo16_ws, part_ws);
    oproj_reduce<<<dim3(512), 256, 0, stream>>>(part_ws, bo, out);
}

// Round 18
// 88.229 us; speedup vs baseline: 1.0777x; 1.0163x over previous
//
#include <hip/hip_runtime.h>

#define T_ 4
#define E_ 1024
#define H_ 16
#define D_ 128
#define C_ 2048
#define QK_SCALE 0.08838834764831845f
#define LOG2E 1.4426950408889634f

typedef short s16x8 __attribute__((ext_vector_type(8)));
typedef float f32x4 __attribute__((ext_vector_type(4)));

__device__ __forceinline__ unsigned short f2bf(float x) {
    unsigned u = __builtin_bit_cast(unsigned, x);
    u = (u + 0x7FFFu + ((u >> 16) & 1u)) >> 16;
    return (unsigned short)u;
}

__device__ __forceinline__ unsigned cvt_pk(float lo, float hi) {
    unsigned r;
    asm("v_cvt_pk_bf16_f32 %0, %1, %2" : "=v"(r) : "v"(lo), "v"(hi));
    return r;
}

#define MFMA16(a, b, c) __builtin_amdgcn_mfma_f32_16x16x32_bf16((a), (b), (c), 0, 0, 0)

__device__ __forceinline__ void gload_lds16(const unsigned short* g, unsigned short* l) {
    __builtin_amdgcn_global_load_lds(
        (const __attribute__((address_space(1))) unsigned int*)g,
        (__attribute__((address_space(3))) unsigned int*)l, 16, 0, 0);
}

// ---------------- fused 7-tensor f32 -> bf16 convert ----------------
__global__ __launch_bounds__(256) void cvt7_kernel(
    const float* __restrict__ q, const float* __restrict__ k, const float* __restrict__ v,
    const float* __restrict__ wq, const float* __restrict__ wk, const float* __restrict__ wv,
    const float* __restrict__ wo,
    unsigned short* __restrict__ base, unsigned short* __restrict__ wo16)
{
    const int b = blockIdx.x;
    const float* src;
    unsigned short* dst;
    int lb;
    if (b < 256)       { src = q;  dst = base;            lb = b; }
    else if (b < 512)  { src = k;  dst = base + 524288;   lb = b - 256; }
    else if (b < 768)  { src = v;  dst = base + 1048576;  lb = b - 512; }
    else if (b < 896)  { src = wq; dst = base + 1572864;  lb = b - 768; }
    else if (b < 1024) { src = wk; dst = base + 1835008;  lb = b - 896; }
    else if (b < 1152) { src = wv; dst = base + 2097152;  lb = b - 1024; }
    else               { src = wo; dst = wo16;            lb = b - 1152; }
    const int i = (lb * 256 + threadIdx.x) * 8;
    float4 a = *reinterpret_cast<const float4*>(src + i);
    float4 c = *reinterpret_cast<const float4*>(src + i + 4);
    s16x8 r;
    r[0] = (short)f2bf(a.x); r[1] = (short)f2bf(a.y);
    r[2] = (short)f2bf(a.z); r[3] = (short)f2bf(a.w);
    r[4] = (short)f2bf(c.x); r[5] = (short)f2bf(c.y);
    r[6] = (short)f2bf(c.z); r[7] = (short)f2bf(c.w);
    *reinterpret_cast<s16x8*>(dst + i) = r;
}

// ---------------- K1: QKV projection (bf16 in, bf16 out, LDS-staged) ----------------
__global__ __launch_bounds__(256) void qkv_kernel(
    const unsigned short* __restrict__ Xq, const unsigned short* __restrict__ Xk,
    const unsigned short* __restrict__ Xv,
    const unsigned short* __restrict__ Wq_, const unsigned short* __restrict__ Wk_,
    const unsigned short* __restrict__ Wv_,
    const float* __restrict__ bq_, const float* __restrict__ bk_, const float* __restrict__ bv_,
    unsigned short* __restrict__ oq, unsigned short* __restrict__ okk,
    unsigned short* __restrict__ ov)
{
    __shared__ unsigned short S[2][128 * 128];  // [0]=X tile, [1]=W tile; reused as Tile

    const int z = blockIdx.z;
    const unsigned short* X = (z == 0) ? Xq : (z == 1) ? Xk : Xv;
    const unsigned short* W = (z == 0) ? Wq_ : (z == 1) ? Wk_ : Wv_;
    const float* Bv = (z == 0) ? bq_ : (z == 1) ? bk_ : bv_;
    unsigned short* out = (z == 0) ? oq : (z == 1) ? okk : ov;
    const float scale = (z == 0) ? (QK_SCALE * LOG2E) : 1.0f;

    const int tid = threadIdx.x;
    const int w = tid >> 6;
    const int lane = tid & 63;
    const int lr = lane & 15;
    const int lg = lane >> 4;
    const int nbase = blockIdx.y * 128;
    const size_t xrow0 = (size_t)blockIdx.x * 128;

#pragma unroll
    for (int it = 0; it < 8; ++it) {
        const int f = it * 256 + tid;
        const int kk = f >> 4;
        const int cs = ((f & 15) * 8) ^ ((kk & 7) << 3);
        gload_lds16(&X[(xrow0 + kk) * D_ + cs], &S[0][f * 8]);
        gload_lds16(&W[(size_t)(nbase + kk) * D_ + cs], &S[1][f * 8]);
    }
    __syncthreads();

    const int key = (lr & 7) << 3;
    s16x8 af[2][4];
#pragma unroll
    for (int mi = 0; mi < 2; ++mi)
#pragma unroll
        for (int kc = 0; kc < 4; ++kc)
            af[mi][kc] = *reinterpret_cast<const s16x8*>(
                &S[0][(w * 32 + mi * 16 + lr) * 128 + ((kc * 32 + lg * 8) ^ key)]);

    f32x4 acc[2][8];
#pragma unroll
    for (int mi = 0; mi < 2; ++mi)
#pragma unroll
        for (int n = 0; n < 8; ++n) acc[mi][n] = f32x4{0.f, 0.f, 0.f, 0.f};

#pragma unroll
    for (int n = 0; n < 8; ++n) {
        s16x8 bf[4];
#pragma unroll
        for (int kc = 0; kc < 4; ++kc)
            bf[kc] = *reinterpret_cast<const s16x8*>(
                &S[1][(n * 16 + lr) * 128 + ((kc * 32 + lg * 8) ^ key)]);
#pragma unroll
        for (int mi = 0; mi < 2; ++mi)
#pragma unroll
            for (int kc = 0; kc < 4; ++kc)
                acc[mi][n] = MFMA16(af[mi][kc], bf[kc], acc[mi][n]);
    }

    float bias[8];
#pragma unroll
    for (int n = 0; n < 8; ++n) bias[n] = Bv[nbase + n * 16 + lr];

    __syncthreads();
    unsigned short* Tile = &S[0][0];  // pitch 136

    if (z < 2) {
#pragma unroll
        for (int mi = 0; mi < 2; ++mi)
#pragma unroll
            for (int i = 0; i < 4; ++i) {
                const int rowl = w * 32 + mi * 16 + lg * 4 + i;
                float v0 = (acc[mi][0][i] + bias[0]) * scale;
                float v1 = (acc[mi][1][i] + bias[1]) * scale;
                float v2 = (acc[mi][2][i] + bias[2]) * scale;
                float v3 = (acc[mi][3][i] + bias[3]) * scale;
                float v4 = (acc[mi][4][i] + bias[4]) * scale;
                float v5 = (acc[mi][5][i] + bias[5]) * scale;
                float v6 = (acc[mi][6][i] + bias[6]) * scale;
                float v7 = (acc[mi][7][i] + bias[7]) * scale;
                union { s16x8 s; unsigned u[4]; } pk;
                pk.u[0] = cvt_pk(v0, v1);
                pk.u[1] = cvt_pk(v2, v3);
                pk.u[2] = cvt_pk(v4, v5);
                pk.u[3] = cvt_pk(v6, v7);
                *reinterpret_cast<s16x8*>(&Tile[rowl * 136 + 8 * lr]) = pk.s;
            }
    } else {
#pragma unroll
        for (int n = 0; n < 8; ++n) {
            union { s16x8 s; unsigned u[4]; } pk;
            pk.u[0] = cvt_pk(acc[0][n][0] + bias[n], acc[0][n][1] + bias[n]);
            pk.u[1] = cvt_pk(acc[0][n][2] + bias[n], acc[0][n][3] + bias[n]);
            pk.u[2] = cvt_pk(acc[1][n][0] + bias[n], acc[1][n][1] + bias[n]);
            pk.u[3] = cvt_pk(acc[1][n][2] + bias[n], acc[1][n][3] + bias[n]);
            *reinterpret_cast<s16x8*>(&Tile[(n * 16 + lr) * 136 + w * 32 + 8 * lg]) = pk.s;
        }
    }
    __syncthreads();

    const int t = (blockIdx.x * 128) >> 10;
    const int e0 = (blockIdx.x * 128) & 1023;
    const int hh = blockIdx.y;
    const int row16 = tid >> 4;
    const int c8 = (tid & 15) * 8;
    if (z < 2) {
        unsigned short* dst = out + (((size_t)(t * H_ + hh) * E_ + e0) * D_);
#pragma unroll
        for (int j = 0; j < 8; ++j) {
            const int row = j * 16 + row16;
            *reinterpret_cast<s16x8*>(dst + (size_t)row * D_ + c8) =
                *reinterpret_cast<const s16x8*>(&Tile[row * 136 + c8]);
        }
    } else {
        unsigned short* dst = out + ((size_t)(t * H_ + hh) * D_) * E_ + e0;
#pragma unroll
        for (int j = 0; j < 8; ++j) {
            const int row = j * 16 + row16;
            *reinterpret_cast<s16x8*>(dst + (size_t)row * E_ + c8) =
                *reinterpret_cast<const s16x8*>(&Tile[row * 136 + c8]);
        }
    }
}

// ---------------- K2: causal flash attention (S^T, 8 waves x 16 q-rows) ----------------
__global__ __launch_bounds__(512, 4) void attn_kernel(
    const unsigned short* __restrict__ Q, const unsigned short* __restrict__ K,
    const unsigned short* __restrict__ Vt, unsigned short* __restrict__ O)
{
    __shared__ unsigned short K_lds[2][64 * 128];   // [kk][c] = K[kv0+kk][c ^ ((kk&7)<<3)]
    __shared__ unsigned short Vt_lds[2][128 * 64];  // [d][p]  = Vperm[d][kv0 + (p ^ ((d&7)<<3))]

    const int tid = threadIdx.x;
    const int w = tid >> 6;
    const int lane = tid & 63;
    const int lr = lane & 15;
    const int g = lane >> 4;
    const int th = blockIdx.x;
    const int t = th >> 4;
    const int h = th & 15;
    const int p = blockIdx.y;
    const int qblk = (p < 4) ? (7 - p) : (p - 4);
    const int q0w = qblk * 128 + w * 16;
    const int nkv = 2 * qblk + 2;

    const unsigned short* Qh = Q + th * (E_ * D_);
    const unsigned short* Kh = K + th * (E_ * D_);
    const unsigned short* Vth = Vt + th * (D_ * E_);

    // hoisted staging sources (2 K-chunks + 2 V-chunks per thread)
    const int fA = tid, fB = 512 + tid;
    const unsigned short* gkA = Kh + (fA >> 4) * D_ + (((fA & 15) * 8) ^ (((fA >> 4) & 7) << 3));
    const unsigned short* gkB = Kh + (fB >> 4) * D_ + (((fB & 15) * 8) ^ (((fB >> 4) & 7) << 3));
    const unsigned short* gvA = Vth + (fA >> 3) * E_ + (((fA & 7) * 8) ^ (((fA >> 3) & 7) << 3));
    const unsigned short* gvB = Vth + (fB >> 3) * E_ + (((fB & 7) * 8) ^ (((fB >> 3) & 7) << 3));

    // Q as B-fragments (cols = q rows), pre-scaled in qkv
    s16x8 qb[4];
#pragma unroll
    for (int kc = 0; kc < 4; ++kc)
        qb[kc] = *reinterpret_cast<const s16x8*>(
            &Qh[(q0w + lr) * D_ + kc * 32 + g * 8]);

    s16x8 ones;
#pragma unroll
    for (int j = 0; j < 8; ++j) ones[j] = (short)0x3F80;

    f32x4 ot[8];
    f32x4 lac;
    float m = -1e30f;
#pragma unroll
    for (int dt = 0; dt < 8; ++dt) ot[dt] = f32x4{0.f, 0.f, 0.f, 0.f};
    lac = f32x4{0.f, 0.f, 0.f, 0.f};

    // prologue: stage tile 0
    gload_lds16(gkA, &K_lds[0][fA * 8]);
    gload_lds16(gkB, &K_lds[0][fB * 8]);
    gload_lds16(gvA, &Vt_lds[0][fA * 8]);
    gload_lds16(gvB, &Vt_lds[0][fB * 8]);
    gkA += 64 * D_; gkB += 64 * D_; gvA += 64; gvB += 64;

    int cur = 0;
    for (int kb = 0; kb < nkv; ++kb) {
        const int kv0 = kb * 64;
        __syncthreads();

        if (kb + 1 < nkv) {
            gload_lds16(gkA, &K_lds[cur ^ 1][fA * 8]);
            gload_lds16(gkB, &K_lds[cur ^ 1][fB * 8]);
            gload_lds16(gvA, &Vt_lds[cur ^ 1][fA * 8]);
            gload_lds16(gvB, &Vt_lds[cur ^ 1][fB * 8]);
            gkA += 64 * D_; gkB += 64 * D_; gvA += 64; gvB += 64;
        }

        if (kv0 <= q0w + 15) {
            const unsigned short* Kb = K_lds[cur];
            const unsigned short* Vb = Vt_lds[cur];
            const int key = (lr & 7) << 3;

            // S^T[kv][q]: 4 kv tiles x 1 q tile
            f32x4 st[4];
#pragma unroll
            for (int kvi = 0; kvi < 4; ++kvi) {
                s16x8 kf[4];
#pragma unroll
                for (int kc = 0; kc < 4; ++kc)
                    kf[kc] = *reinterpret_cast<const s16x8*>(
                        &Kb[(kvi * 16 + lr) * 128 + ((kc * 32 + g * 8) ^ key)]);
                f32x4 a = f32x4{0.f, 0.f, 0.f, 0.f};
#pragma unroll
                for (int kc = 0; kc < 4; ++kc) a = MFMA16(kf[kc], qb[kc], a);
                st[kvi] = a;
            }

            // causal mask: only diagonal tiles (wave-uniform branch)
            if (kv0 + 63 > q0w) {
                const int q = q0w + lr;
#pragma unroll
                for (int kvi = 0; kvi < 4; ++kvi)
#pragma unroll
                    for (int i = 0; i < 4; ++i) {
                        const int kv = kv0 + kvi * 16 + g * 4 + i;
                        if (kv > q) st[kvi][i] = -1e30f;
                    }
            }

            // per-q-column max: lane-local over 16 vals, then xor-16/32
            float a0 = fmaxf(fmaxf(st[0][0], st[0][1]), fmaxf(st[0][2], st[0][3]));
            float a1 = fmaxf(fmaxf(st[1][0], st[1][1]), fmaxf(st[1][2], st[1][3]));
            float a2 = fmaxf(fmaxf(st[2][0], st[2][1]), fmaxf(st[2][2], st[2][3]));
            float a3 = fmaxf(fmaxf(st[3][0], st[3][1]), fmaxf(st[3][2], st[3][3]));
            float pm = fmaxf(fmaxf(a0, a1), fmaxf(a2, a3));
            pm = fmaxf(pm, __shfl_xor(pm, 16));
            pm = fmaxf(pm, __shfl_xor(pm, 32));

            // defer-max: rescale only when max grew past threshold
            if (__any(pm > m + 8.f)) {
                const float mn = fmaxf(m, pm);
                const float esc = exp2f(m - mn);
                m = mn;
                lac *= esc;
#pragma unroll
                for (int dt = 0; dt < 8; ++dt) ot[dt] *= esc;
            }

            // P^T -> bf16 B-frags in registers
            s16x8 pb[2];
#pragma unroll
            for (int kc = 0; kc < 2; ++kc) {
                float e0 = exp2f(st[2 * kc][0] - m);
                float e1 = exp2f(st[2 * kc][1] - m);
                float e2 = exp2f(st[2 * kc][2] - m);
                float e3 = exp2f(st[2 * kc][3] - m);
                float f0 = exp2f(st[2 * kc + 1][0] - m);
                float f1 = exp2f(st[2 * kc + 1][1] - m);
                float f2 = exp2f(st[2 * kc + 1][2] - m);
                float f3 = exp2f(st[2 * kc + 1][3] - m);
                union { s16x8 s; unsigned u[4]; } pk;
                pk.u[0] = cvt_pk(e0, e1);
                pk.u[1] = cvt_pk(e2, e3);
                pk.u[2] = cvt_pk(f0, f1);
                pk.u[3] = cvt_pk(f2, f3);
                pb[kc] = pk.s;
            }

            // row-sum via ones-MFMA
            lac = MFMA16(ones, pb[0], lac);
            lac = MFMA16(ones, pb[1], lac);

            // O^T += V^T @ P^T  (A-frag: ONE b128 read, conflict-free)
#pragma unroll
            for (int dt = 0; dt < 8; ++dt) {
                const int rb = (dt * 16 + lr) * 64;
#pragma unroll
                for (int kc = 0; kc < 2; ++kc) {
                    s16x8 va = *reinterpret_cast<const s16x8*>(
                        &Vb[rb + ((kc * 32 + 8 * g) ^ key)]);
                    ot[dt] = MFMA16(va, pb[kc], ot[dt]);
                }
            }
        }
        cur ^= 1;
    }

    // epilogue: lane holds q=q0w+lr, d=dt*16+g*4+i -> b64 stores
    unsigned short* Ob = O + (size_t)t * E_ * C_ + h * D_;
    const float rl = 1.0f / lac[0];
    const int q = q0w + lr;
#pragma unroll
    for (int dt = 0; dt < 8; ++dt) {
        uint2 val;
        val.x = cvt_pk(ot[dt][0] * rl, ot[dt][1] * rl);
        val.y = cvt_pk(ot[dt][2] * rl, ot[dt][3] * rl);
        *reinterpret_cast<uint2*>(&Ob[(size_t)q * C_ + dt * 16 + 4 * g]) = val;
    }
}

// ---------------- K3a: output projection partials (M=4096, N=128, K=2048/2) ----------------
// grid (256, 2): x = 16-row tile, y = K-half. Plain stores to part[y].
__global__ __launch_bounds__(256) void oproj_partial(
    const unsigned short* __restrict__ A, const unsigned short* __restrict__ Wo16,
    float* __restrict__ part)
{
    const int tid = threadIdx.x;
    const int w = tid >> 6;
    const int lane = tid & 63;
    const int lr = lane & 15;
    const int lg = lane >> 4;
    const int mbase = blockIdx.x * 16;
    const int ncol = w * 32;
    const int k0 = blockIdx.y * 1024;
    float* myp = part + (size_t)blockIdx.y * (4096 * 128);

    f32x4 acc0 = f32x4{0.f, 0.f, 0.f, 0.f};
    f32x4 acc1 = f32x4{0.f, 0.f, 0.f, 0.f};
    const unsigned short* Arow = A + (size_t)(mbase + lr) * C_ + k0;
    const unsigned short* W0 = Wo16 + (size_t)(ncol + lr) * C_ + k0;
    const unsigned short* W1 = Wo16 + (size_t)(ncol + 16 + lr) * C_ + k0;

#pragma unroll 8
    for (int kb = 0; kb < 32; ++kb) {
        const int ko = kb * 32 + lg * 8;
        s16x8 af = *reinterpret_cast<const s16x8*>(Arow + ko);
        s16x8 b0 = *reinterpret_cast<const s16x8*>(W0 + ko);
        s16x8 b1 = *reinterpret_cast<const s16x8*>(W1 + ko);
        acc0 = MFMA16(af, b0, acc0);
        acc1 = MFMA16(af, b1, acc1);
    }

#pragma unroll
    for (int n = 0; n < 2; ++n) {
        const f32x4 acc = n ? acc1 : acc0;
        const int col = ncol + n * 16 + lr;
#pragma unroll
        for (int i = 0; i < 4; ++i)
            myp[(mbase + lg * 4 + i) * D_ + col] = acc[i];
    }
}

// ---------------- K3b: reduce 2 partials + bias -> out ----------------
__global__ __launch_bounds__(256) void oproj_reduce(
    const float* __restrict__ part, const float* __restrict__ bo,
    float* __restrict__ out)
{
    const int iv = blockIdx.x * 256 + threadIdx.x;
    const size_t seg = (size_t)4096 * 128;
    float4 s = *reinterpret_cast<const float4*>(part + (size_t)iv * 4);
    float4 v = *reinterpret_cast<const float4*>(part + seg + (size_t)iv * 4);
    s.x += v.x; s.y += v.y; s.z += v.z; s.w += v.w;
    const float4 b = *reinterpret_cast<const float4*>(bo + ((iv & 31) * 4));
    s.x += b.x; s.y += b.y; s.z += b.z; s.w += b.w;
    *reinterpret_cast<float4*>(out + (size_t)iv * 4) = s;
}

extern "C" void kernel_launch(void* const* d_in, const int* in_sizes, int n_in,
                              void* d_out, int out_size, void* d_ws, size_t ws_size,
                              hipStream_t stream) {
    const float* key   = (const float*)d_in[0];
    const float* value = (const float*)d_in[1];
    const float* query = (const float*)d_in[2];
    const float* Wq = (const float*)d_in[3];
    const float* bq = (const float*)d_in[4];
    const float* Wk = (const float*)d_in[5];
    const float* bk = (const float*)d_in[6];
    const float* Wv = (const float*)d_in[7];
    const float* bv = (const float*)d_in[8];
    const float* Wo = (const float*)d_in[9];
    const float* bo = (const float*)d_in[10];
    float* out = (float*)d_out;

    unsigned short* ws = (unsigned short*)d_ws;
    const size_t QKV_ELEMS = (size_t)T_ * H_ * E_ * D_;  // 8388608
    unsigned short* q_ws = ws;
    unsigned short* k_ws = ws + QKV_ELEMS;
    unsigned short* v_ws = ws + 2 * QKV_ELEMS;            // V^T [T][H][D][E], e-permuted
    unsigned short* att_ws = ws + 3 * QKV_ELEMS;
    unsigned short* wo16_ws = ws + 4 * QKV_ELEMS;
    float* part_ws = (float*)k_ws;                        // k_ws dead after attn (4MB used)

    unsigned short* xq16 = att_ws;
    unsigned short* xk16 = att_ws + 524288;
    unsigned short* xv16 = att_ws + 1048576;
    unsigned short* wq16 = att_ws + 1572864;
    unsigned short* wk16 = att_ws + 1835008;
    unsigned short* wv16 = att_ws + 2097152;

    cvt7_kernel<<<dim3(1280), 256, 0, stream>>>(query, key, value, Wq, Wk, Wv, Wo,
                                                att_ws, wo16_ws);
    qkv_kernel<<<dim3(32, 16, 3), 256, 0, stream>>>(xq16, xk16, xv16,
                                                    wq16, wk16, wv16,
                                                    bq, bk, bv,
                                                    q_ws, k_ws, v_ws);
    attn_kernel<<<dim3(64, 8), 512, 0, stream>>>(q_ws, k_ws, v_ws, att_ws);
    oproj_partial<<<dim3(256, 2), 256, 0, stream>>>(att_ws, wo16_ws, part_ws);
    oproj_reduce<<<dim3(512), 256, 0, stream>>>(part_ws, bo, out);
}